// Round 5
// baseline (419.425 us; speedup 1.0000x reference)
//
#include <hip/hip_runtime.h>
#include <hip/hip_fp16.h>
#include <math.h>

#define NLV 8
#define NF 4
#define HSZ 8192
#define TRES 25
#define PRIME 2654435761u

struct Scales { float s[NLV]; };

// Blend two time slices into one fp16 table in workspace.
// Layout per level l: 8192 slots x 8 B, slot h = {half2(f0,f1), half2(f2,f3)}
// -> one ds_read_b64 per bilinear corner in the encode kernel.
__global__ __launch_bounds__(256) void blend_kernel(
    const float* __restrict__ table, const float* __restrict__ tptr,
    __half2* __restrict__ bt)
{
    int i = blockIdx.x * 256 + threadIdx.x;       // 0..65535 = l*8192 + h
    float t = *tptr;
    float idx = t * (float)(TRES - 1);            // fp32, matches ref
    float fi1 = floorf(idx);
    float fi2 = ceilf(idx);
    float w2 = idx - fi1;
    float w1 = 1.0f - w2;
    size_t off1 = (size_t)(int)fi1 * (size_t)(NLV * HSZ * NF);
    size_t off2 = (size_t)(int)fi2 * (size_t)(NLV * HSZ * NF);
    float4 a = ((const float4*)(table + off1))[i];
    float4 b = ((const float4*)(table + off2))[i];
    float4 r;
    r.x = w1 * a.x + w2 * b.x;
    r.y = w1 * a.y + w2 * b.y;
    r.z = w1 * a.z + w2 * b.z;
    r.w = w1 * a.w + w2 * b.w;
    bt[2 * (size_t)i]     = __floats2half2_rn(r.x, r.y);
    bt[2 * (size_t)i + 1] = __floats2half2_rn(r.z, r.w);
}

__device__ __forceinline__ float2 h2f(unsigned u) {
    return __half22float2(__builtin_bit_cast(__half2, u));
}

// One level, one point: 4 hashed corners, each an 8-B LDS read, bilinear blend.
__device__ __forceinline__ float4 gather_lvl(const uint2* tbl, float2 p, float scale)
{
    // separate mul+add rounding (no fma) to match numpy floor/frac exactly
    float px = __fadd_rn(__fmul_rn(p.x, scale), 0.5f);
    float py = __fadd_rn(__fmul_rn(p.y, scale), 0.5f);
    float fx0 = floorf(px), fy0 = floorf(py);
    float fx = px - fx0, fy = py - fy0;
    unsigned ix = (unsigned)(int)fx0;
    unsigned iy = (unsigned)(int)fy0;
    unsigned hy0 = iy * PRIME;
    unsigned hy1 = hy0 + PRIME;                   // (iy+1)*PRIME mod 2^32
    unsigned h00 = (ix         ^ hy0) & (HSZ - 1);
    unsigned h01 = (ix         ^ hy1) & (HSZ - 1);
    unsigned h10 = ((ix + 1u)  ^ hy0) & (HSZ - 1);
    unsigned h11 = ((ix + 1u)  ^ hy1) & (HSZ - 1);
    uint2 v00 = tbl[h00];
    uint2 v01 = tbl[h01];
    uint2 v10 = tbl[h10];
    uint2 v11 = tbl[h11];
    float gx = 1.0f - fx, gy = 1.0f - fy;
    float w00 = gx * gy, w01 = gx * fy, w10 = fx * gy, w11 = fx * fy;
    float2 a00 = h2f(v00.x), b00 = h2f(v00.y);
    float2 a01 = h2f(v01.x), b01 = h2f(v01.y);
    float2 a10 = h2f(v10.x), b10 = h2f(v10.y);
    float2 a11 = h2f(v11.x), b11 = h2f(v11.y);
    float4 r;
    r.x = w00 * a00.x + w01 * a01.x + w10 * a10.x + w11 * a11.x;
    r.y = w00 * a00.y + w01 * a01.y + w10 * a10.y + w11 * a11.y;
    r.z = w00 * b00.x + w01 * b01.x + w10 * b10.x + w11 * b11.x;
    r.w = w00 * b00.y + w01 * b01.y + w10 * b10.y + w11 * b11.y;
    return r;
}

// Stage one level (64 KB) into LDS via direct global->LDS DMA, 4 x 16 B per
// thread. Dest is linear: per wave, base + lane*16 (the required pattern).
__device__ __forceinline__ void stage_dma(const float4* __restrict__ src,
                                          float4* dst, int tid)
{
    #pragma unroll
    for (int k = 0; k < 4; ++k) {
        __builtin_amdgcn_global_load_lds(
            (const __attribute__((address_space(1))) unsigned int*)(src + tid + k * 1024),
            (__attribute__((address_space(3))) unsigned int*)(dst + tid + k * 1024),
            16, 0, 0);
    }
}

// 2 points/thread (2048 pts/block, 977 blocks): halves L2 staging traffic
// (1 GB -> 0.5 GB) and total barrier count vs round 4, keeping its proven
// structure. CRITICAL (rounds 1-3 lesson): accumulators are 16 NAMED float4
// scalars, never arrays -> no alloca -> no scratch. waves_per_eu(4,4):
// occupancy is LDS-capped at 4 waves/EU (128 KB/block) anyway; pins the
// allocator budget at 128 VGPRs. Peak live ~110 regs (64 acc + points +
// gather temps) fits.
// Pipeline per phase: issue next level's DMA -> s_waitcnt vmcnt(4) (waits
// ONLY the previous level's 4 loads; the 4 just issued stay in flight under
// this phase's gathers) -> s_barrier -> gather x2 -> s_barrier.
__global__ __launch_bounds__(1024)
__attribute__((amdgpu_waves_per_eu(4, 4)))
void encode_kernel(
    const float* __restrict__ x, const float4* __restrict__ bt,
    float* __restrict__ out, int npts, Scales sc)
{
    __shared__ float4 smem[2][4096];              // 2 x 64 KB double buffer
    int tid = threadIdx.x;
    int base = blockIdx.x * 2048 + tid;
    int n0 = base, n1 = base + 1024;
    int c0 = n0 < npts ? n0 : npts - 1;           // clamp reads; store guarded
    int c1 = n1 < npts ? n1 : npts - 1;
    float2 p0 = ((const float2*)x)[c0];
    float2 p1 = ((const float2*)x)[c1];

    // prologue: DMA level 0 into buffer 0
    stage_dma(bt, smem[0], tid);

    float4 a0, a1, a2, a3, a4, a5, a6, a7;        // point 0 accumulators
    float4 b0, b1, b2, b3, b4, b5, b6, b7;        // point 1 accumulators

#define PHASE(L, A, B)                                                       \
    {                                                                        \
        if ((L) < NLV - 1)                                                   \
            stage_dma(bt + (size_t)((L) + 1) * 4096, smem[((L) + 1) & 1], tid);\
        if ((L) < NLV - 1) asm volatile("s_waitcnt vmcnt(4)" ::: "memory");  \
        else               asm volatile("s_waitcnt vmcnt(0)" ::: "memory");  \
        __builtin_amdgcn_s_barrier();                                        \
        __builtin_amdgcn_sched_barrier(0);                                   \
        {                                                                    \
            const uint2* tbl = (const uint2*)smem[(L) & 1];                  \
            float s = sc.s[(L)];                                             \
            A = gather_lvl(tbl, p0, s);                                      \
            B = gather_lvl(tbl, p1, s);                                      \
        }                                                                    \
        if ((L) < NLV - 1) {                                                 \
            __builtin_amdgcn_sched_barrier(0);                               \
            __builtin_amdgcn_s_barrier();                                    \
        }                                                                    \
    }

    PHASE(0, a0, b0)
    PHASE(1, a1, b1)
    PHASE(2, a2, b2)
    PHASE(3, a3, b3)
    PHASE(4, a4, b4)
    PHASE(5, a5, b5)
    PHASE(6, a6, b6)
    PHASE(7, a7, b7)
#undef PHASE

    // full 128-B line per point, 8 contiguous float4 stores back-to-back
    // (L2 merges these into full lines -> WRITE = ideal, no allocate-fetch)
    if (n0 < npts) {
        float4* o = (float4*)(out + (size_t)n0 * 32);
        o[0] = a0; o[1] = a1; o[2] = a2; o[3] = a3;
        o[4] = a4; o[5] = a5; o[6] = a6; o[7] = a7;
    }
    if (n1 < npts) {
        float4* o = (float4*)(out + (size_t)n1 * 32);
        o[0] = b0; o[1] = b1; o[2] = b2; o[3] = b3;
        o[4] = b4; o[5] = b5; o[6] = b6; o[7] = b7;
    }
}

extern "C" void kernel_launch(void* const* d_in, const int* in_sizes, int n_in,
                              void* d_out, int out_size, void* d_ws, size_t ws_size,
                              hipStream_t stream) {
    const float* x     = (const float*)d_in[0];
    const float* t     = (const float*)d_in[1];
    const float* table = (const float*)d_in[2];
    float* out = (float*)d_out;
    __half2* bt = (__half2*)d_ws;       // 512 KB blended fp16 table

    int npts = in_sizes[0] / 2;

    Scales sc;
    const double l2p = log2(32768.0 / 512.0) / 7.0;   // exactly as numpy
    for (int l = 0; l < NLV; ++l)
        sc.s[l] = (float)(exp2((double)l * l2p) * 512.0 - 1.0);

    blend_kernel<<<(NLV * HSZ) / 256, 256, 0, stream>>>(table, t, bt);

    int nblocks = (npts + 2047) / 2048;
    encode_kernel<<<nblocks, 1024, 0, stream>>>(
        x, (const float4*)bt, out, npts, sc);
}

// Round 6
// 383.041 us; speedup vs baseline: 1.0950x; 1.0950x over previous
//
#include <hip/hip_runtime.h>
#include <hip/hip_fp16.h>
#include <math.h>

#define NLV 8
#define NF 4
#define HSZ 8192
#define TRES 25
#define PRIME 2654435761u

struct Scales { float s[NLV]; };

// Blend two time slices into one fp16 table in workspace.
// Layout per level l: 8192 slots x 8 B, slot h = {half2(f0,f1), half2(f2,f3)}
// -> one ds_read_b64 per bilinear corner in the encode kernel.
__global__ __launch_bounds__(256) void blend_kernel(
    const float* __restrict__ table, const float* __restrict__ tptr,
    __half2* __restrict__ bt)
{
    int i = blockIdx.x * 256 + threadIdx.x;       // 0..65535 = l*8192 + h
    float t = *tptr;
    float idx = t * (float)(TRES - 1);            // fp32, matches ref
    float fi1 = floorf(idx);
    float fi2 = ceilf(idx);
    float w2 = idx - fi1;
    float w1 = 1.0f - w2;
    size_t off1 = (size_t)(int)fi1 * (size_t)(NLV * HSZ * NF);
    size_t off2 = (size_t)(int)fi2 * (size_t)(NLV * HSZ * NF);
    float4 a = ((const float4*)(table + off1))[i];
    float4 b = ((const float4*)(table + off2))[i];
    float4 r;
    r.x = w1 * a.x + w2 * b.x;
    r.y = w1 * a.y + w2 * b.y;
    r.z = w1 * a.z + w2 * b.z;
    r.w = w1 * a.w + w2 * b.w;
    bt[2 * (size_t)i]     = __floats2half2_rn(r.x, r.y);
    bt[2 * (size_t)i + 1] = __floats2half2_rn(r.z, r.w);
}

__device__ __forceinline__ float2 h2f(unsigned u) {
    return __half22float2(__builtin_bit_cast(__half2, u));
}

// One level, one point: 4 hashed corners, each an 8-B LDS read, bilinear blend.
__device__ __forceinline__ float4 gather_lvl(const uint2* tbl, float2 p, float scale)
{
    // separate mul+add rounding (no fma) to match numpy floor/frac exactly
    float px = __fadd_rn(__fmul_rn(p.x, scale), 0.5f);
    float py = __fadd_rn(__fmul_rn(p.y, scale), 0.5f);
    float fx0 = floorf(px), fy0 = floorf(py);
    float fx = px - fx0, fy = py - fy0;
    unsigned ix = (unsigned)(int)fx0;
    unsigned iy = (unsigned)(int)fy0;
    unsigned hy0 = iy * PRIME;
    unsigned hy1 = hy0 + PRIME;                   // (iy+1)*PRIME mod 2^32
    unsigned h00 = (ix         ^ hy0) & (HSZ - 1);
    unsigned h01 = (ix         ^ hy1) & (HSZ - 1);
    unsigned h10 = ((ix + 1u)  ^ hy0) & (HSZ - 1);
    unsigned h11 = ((ix + 1u)  ^ hy1) & (HSZ - 1);
    uint2 v00 = tbl[h00];
    uint2 v01 = tbl[h01];
    uint2 v10 = tbl[h10];
    uint2 v11 = tbl[h11];
    float gx = 1.0f - fx, gy = 1.0f - fy;
    float w00 = gx * gy, w01 = gx * fy, w10 = fx * gy, w11 = fx * fy;
    float2 a00 = h2f(v00.x), b00 = h2f(v00.y);
    float2 a01 = h2f(v01.x), b01 = h2f(v01.y);
    float2 a10 = h2f(v10.x), b10 = h2f(v10.y);
    float2 a11 = h2f(v11.x), b11 = h2f(v11.y);
    float4 r;
    r.x = w00 * a00.x + w01 * a01.x + w10 * a10.x + w11 * a11.x;
    r.y = w00 * a00.y + w01 * a01.y + w10 * a10.y + w11 * a11.y;
    r.z = w00 * b00.x + w01 * b01.x + w10 * b10.x + w11 * b11.x;
    r.w = w00 * b00.y + w01 * b01.y + w10 * b10.y + w11 * b11.y;
    return r;
}

// Stage one level (64 KB) into LDS via direct global->LDS DMA, 4 x 16 B per
// thread. Dest is linear: per wave, base + lane*16 (the required pattern).
__device__ __forceinline__ void stage_dma(const float4* __restrict__ src,
                                          float4* dst, int tid)
{
    #pragma unroll
    for (int k = 0; k < 4; ++k) {
        __builtin_amdgcn_global_load_lds(
            (const __attribute__((address_space(1))) unsigned int*)(src + tid + k * 1024),
            (__attribute__((address_space(3))) unsigned int*)(dst + tid + k * 1024),
            16, 0, 0);
    }
}

// 1 point/thread, SINGLE 64 KB LDS buffer -> 2 blocks co-resident per CU
// (2048 threads = full occupancy). Round-4's 128 KB double buffer forced
// 1 block/CU: every per-phase stall (DMA issue, L2 latency, barrier skew)
// was a CU-wide dead slot. With 2 independent blocks, block B's gather phase
// fills block A's staging stall and vice versa -- cross-block overlap
// replaces the intra-block double buffer.
// Per phase: DMA level l -> s_waitcnt vmcnt(0) -> s_barrier (data ready) ->
// gather -> s_barrier (all reads done before next phase's DMA overwrites).
// LESSON (rounds 1/2/3/5): 1024-thread kernels get a hard 64-VGPR budget;
// accumulators MUST be named scalars and 1 pt/thread (~56 VGPRs, fits).
__global__ __launch_bounds__(1024) void encode_kernel(
    const float* __restrict__ x, const float4* __restrict__ bt,
    float* __restrict__ out, int npts, Scales sc)
{
    __shared__ float4 smem[4096];                 // 64 KB, single buffer
    int tid = threadIdx.x;
    int n0 = blockIdx.x * 1024 + tid;
    int c0 = n0 < npts ? n0 : npts - 1;           // clamp reads; store guarded
    float2 p = ((const float2*)x)[c0];

    float4 a0, a1, a2, a3, a4, a5, a6, a7;

#define PHASE(L, ACC)                                                        \
    {                                                                        \
        stage_dma(bt + (size_t)(L) * 4096, smem, tid);                       \
        asm volatile("s_waitcnt vmcnt(0)" ::: "memory");                     \
        __builtin_amdgcn_s_barrier();             /* all waves' DMA landed */\
        __builtin_amdgcn_sched_barrier(0);                                   \
        ACC = gather_lvl((const uint2*)smem, p, sc.s[(L)]);                  \
        __builtin_amdgcn_sched_barrier(0);                                   \
        if ((L) < NLV - 1) __builtin_amdgcn_s_barrier(); /* reads done */    \
    }

    PHASE(0, a0)
    PHASE(1, a1)
    PHASE(2, a2)
    PHASE(3, a3)
    PHASE(4, a4)
    PHASE(5, a5)
    PHASE(6, a6)
    PHASE(7, a7)
#undef PHASE

    // full 128-B line per point, 8 contiguous float4 stores back-to-back
    // (L2 merges these into full lines -> WRITE = ideal, no allocate-fetch)
    if (n0 < npts) {
        float4* o = (float4*)(out + (size_t)n0 * 32);
        o[0] = a0; o[1] = a1; o[2] = a2; o[3] = a3;
        o[4] = a4; o[5] = a5; o[6] = a6; o[7] = a7;
    }
}

extern "C" void kernel_launch(void* const* d_in, const int* in_sizes, int n_in,
                              void* d_out, int out_size, void* d_ws, size_t ws_size,
                              hipStream_t stream) {
    const float* x     = (const float*)d_in[0];
    const float* t     = (const float*)d_in[1];
    const float* table = (const float*)d_in[2];
    float* out = (float*)d_out;
    __half2* bt = (__half2*)d_ws;       // 512 KB blended fp16 table

    int npts = in_sizes[0] / 2;

    Scales sc;
    const double l2p = log2(32768.0 / 512.0) / 7.0;   // exactly as numpy
    for (int l = 0; l < NLV; ++l)
        sc.s[l] = (float)(exp2((double)l * l2p) * 512.0 - 1.0);

    blend_kernel<<<(NLV * HSZ) / 256, 256, 0, stream>>>(table, t, bt);

    int nblocks = (npts + 1023) / 1024;
    encode_kernel<<<nblocks, 1024, 0, stream>>>(
        x, (const float4*)bt, out, npts, sc);
}